// Round 2
// 1015.765 us; speedup vs baseline: 1.7225x; 1.7225x over previous
//
#include <hip/hip_runtime.h>

static constexpr int kN  = 4096;   // nodes
static constexpr int kE  = 128;    // embed
static constexpr int kH  = 8;      // heads
static constexpr int kD  = 16;     // head dim
static constexpr int kNE = 65536;  // edges

typedef float f4 __attribute__((ext_vector_type(4)));  // native vec for nontemporal store

// ---------------- Kernel 1: type-specific QKV projections ----------------
// grid kN, block kE(=128). y[n,f] = sum_e x[n,e]*W[t][e,f] + b[t][f]
__global__ void proj_kernel(const float* __restrict__ q_in, const float* __restrict__ k_in,
                            const float* __restrict__ v_in,
                            const float* __restrict__ Wq, const float* __restrict__ bq,
                            const float* __restrict__ Wk, const float* __restrict__ bk,
                            const float* __restrict__ Wv, const float* __restrict__ bv,
                            const int* __restrict__ node_types,
                            float* __restrict__ Q, float* __restrict__ K, float* __restrict__ V) {
    const int n = blockIdx.x;
    const int f = threadIdx.x;
    __shared__ float xq[kE], xk[kE], xv[kE];
    xq[f] = q_in[n * kE + f];
    xk[f] = k_in[n * kE + f];
    xv[f] = v_in[n * kE + f];
    __syncthreads();
    const int t = node_types[n];
    const float* wq = Wq + (size_t)t * kE * kE;
    const float* wk = Wk + (size_t)t * kE * kE;
    const float* wv = Wv + (size_t)t * kE * kE;
    float aq = bq[t * kE + f], ak = bk[t * kE + f], av = bv[t * kE + f];
#pragma unroll 8
    for (int e = 0; e < kE; ++e) {
        aq += xq[e] * wq[e * kE + f];
        ak += xk[e] * wk[e * kE + f];
        av += xv[e] * wv[e * kE + f];
    }
    Q[n * kE + f] = aq;
    K[n * kE + f] = ak;
    V[n * kE + f] = av;
}

// ---------------- CSR build (edges grouped by target row) ----------------
__global__ void csr_zero_kernel(int* __restrict__ counts) {
    counts[blockIdx.x * 256 + threadIdx.x] = 0;
}

__global__ void csr_count_kernel(const int* __restrict__ edge_index, int* __restrict__ counts) {
    const int e = blockIdx.x * 256 + threadIdx.x;
    atomicAdd(&counts[edge_index[kNE + e]], 1);  // tgt
}

// 1 block, 1024 threads, 4 counts each: exclusive prefix -> P (row starts)
__global__ void csr_scan_kernel(const int* __restrict__ counts, int* __restrict__ P) {
    __shared__ int buf[1024];
    const int t = threadIdx.x;
    int c[4];
    int s = 0;
#pragma unroll
    for (int u = 0; u < 4; ++u) { c[u] = counts[t * 4 + u]; s += c[u]; }
    buf[t] = s;
    __syncthreads();
    int v = s;
    for (int off = 1; off < 1024; off <<= 1) {
        const int add = (t >= off) ? buf[t - off] : 0;
        __syncthreads();
        v += add;
        buf[t] = v;
        __syncthreads();
    }
    int run = v - s;  // exclusive prefix
#pragma unroll
    for (int u = 0; u < 4; ++u) { P[t * 4 + u] = run; run += c[u]; }
}

// scatter: after this P[i] == END of row i (start of row i+1). entry = src | et<<12 (fits u16)
__global__ void csr_scatter_kernel(const int* __restrict__ edge_index,
                                   const int* __restrict__ edge_types,
                                   int* __restrict__ P, unsigned short* __restrict__ entries) {
    const int e = blockIdx.x * 256 + threadIdx.x;
    const int src = edge_index[e];
    const int tgt = edge_index[kNE + e];
    const int et  = edge_types[e];
    const int pos = atomicAdd(&P[tgt], 1);
    entries[pos] = (unsigned short)(src | (et << 12));
}

// ---------------- Kernel 2: fused scores + bias + softmax + attn-write + PV ----------------
// grid (kN/4, kH), block 256 (4 waves). LDS: S[4][4096] = 64 KB, 2 blocks/CU.
// wave w owns j-range [w*1024, w*1024+1024) for scores/PV, and row i0+w for bias/softmax.
__global__ __launch_bounds__(256, 2) void attn_fused_kernel(
        const float* __restrict__ Q, const float* __restrict__ K, const float* __restrict__ V,
        const int* __restrict__ Pend, const unsigned short* __restrict__ entries,
        const float* __restrict__ edge_bias,
        float* __restrict__ attn, float* __restrict__ OT) {
    const int i0 = blockIdx.x * 4;
    const int h  = blockIdx.y;
    const int t  = threadIdx.x;
    const int w  = t >> 6;
    const int lane = t & 63;
    const int jw = w * 1024;

    __shared__ float S[4][kN];        // 64 KB
    __shared__ float ebias_s[3 * kH];
    __shared__ float inv_s[4];
    __shared__ float red[4][64];

    if (t < 3 * kH) ebias_s[t] = edge_bias[t];

    // ---- phase 1: scores. lane owns column j, computes all 4 rows (K load amortized x4) ----
    {
        float4 qv[4][4];
#pragma unroll
        for (int r = 0; r < 4; ++r) {
            const float4* qp = (const float4*)(Q + (size_t)(i0 + r) * kE + h * kD);
#pragma unroll
            for (int u = 0; u < 4; ++u) qv[r][u] = qp[u];
        }
#pragma unroll 2
        for (int k = 0; k < 16; ++k) {
            const int j = jw + k * 64 + lane;
            const float4* kp = (const float4*)(K + (size_t)j * kE + h * kD);
            const float4 k0 = kp[0], k1 = kp[1], k2 = kp[2], k3 = kp[3];
#pragma unroll
            for (int r = 0; r < 4; ++r) {
                float a = qv[r][0].x * k0.x + qv[r][0].y * k0.y + qv[r][0].z * k0.z + qv[r][0].w * k0.w;
                a += qv[r][1].x * k1.x + qv[r][1].y * k1.y + qv[r][1].z * k1.z + qv[r][1].w * k1.w;
                a += qv[r][2].x * k2.x + qv[r][2].y * k2.y + qv[r][2].z * k2.z + qv[r][2].w * k2.w;
                a += qv[r][3].x * k3.x + qv[r][3].y * k3.y + qv[r][3].z * k3.z + qv[r][3].w * k3.w;
                S[r][j] = a * 0.25f;  // 1/sqrt(16)
            }
        }
    }
    __syncthreads();

    // ---- phase 2: edge bias into LDS (wave w handles row i0+w; LDS atomics, dup-safe) ----
    {
        const int i = i0 + w;
        const int beg = (i == 0) ? 0 : Pend[i - 1];
        const int end = Pend[i];
        for (int idx = beg + lane; idx < end; idx += 64) {
            const unsigned int en = entries[idx];
            atomicAdd(&S[w][en & 0xFFFu], ebias_s[(en >> 12) * kH + h]);
        }
    }
    __syncthreads();

    // ---- phase 3: softmax over row i0+w; write normalized attn (nontemporal) ----
    {
        float4* srow4 = (float4*)&S[w][0];
        float m = -3.4e38f;
#pragma unroll 4
        for (int k = 0; k < 16; ++k) {
            const float4 sv = srow4[k * 64 + lane];
            m = fmaxf(m, fmaxf(fmaxf(sv.x, sv.y), fmaxf(sv.z, sv.w)));
        }
#pragma unroll
        for (int off = 32; off > 0; off >>= 1) m = fmaxf(m, __shfl_xor(m, off, 64));
        float sum = 0.f;
#pragma unroll 2
        for (int k = 0; k < 16; ++k) {
            float4 sv = srow4[k * 64 + lane];
            sv.x = __expf(sv.x - m); sv.y = __expf(sv.y - m);
            sv.z = __expf(sv.z - m); sv.w = __expf(sv.w - m);
            srow4[k * 64 + lane] = sv;  // keep unnormalized e in LDS for PV
            sum += (sv.x + sv.y) + (sv.z + sv.w);
        }
#pragma unroll
        for (int off = 32; off > 0; off >>= 1) sum += __shfl_xor(sum, off, 64);
        const float inv = 1.f / sum;
        if (lane == 0) inv_s[w] = inv;
        f4* arow = (f4*)(attn + ((size_t)h * kN + (i0 + w)) * kN);
#pragma unroll 2
        for (int k = 0; k < 16; ++k) {
            const float4 ev = srow4[k * 64 + lane];
            f4 pv;
            pv.x = ev.x * inv; pv.y = ev.y * inv; pv.z = ev.z * inv; pv.w = ev.w * inv;
            __builtin_nontemporal_store(pv, &arow[k * 64 + lane]);
        }
    }
    __syncthreads();

    // ---- phase 4: PV. lane owns j (distinct LDS reads), 64 independent accumulators ----
    {
        float A[64];  // A[r*16+d]
#pragma unroll
        for (int m2 = 0; m2 < 64; ++m2) A[m2] = 0.f;
#pragma unroll 2
        for (int k = 0; k < 16; ++k) {
            const int j = jw + k * 64 + lane;
            const float4* vp = (const float4*)(V + (size_t)j * kE + h * kD);
            const float4 v0 = vp[0], v1 = vp[1], v2 = vp[2], v3 = vp[3];
#pragma unroll
            for (int r = 0; r < 4; ++r) {
                const float s = S[r][j];
                A[r*16+ 0] += s * v0.x; A[r*16+ 1] += s * v0.y; A[r*16+ 2] += s * v0.z; A[r*16+ 3] += s * v0.w;
                A[r*16+ 4] += s * v1.x; A[r*16+ 5] += s * v1.y; A[r*16+ 6] += s * v1.z; A[r*16+ 7] += s * v1.w;
                A[r*16+ 8] += s * v2.x; A[r*16+ 9] += s * v2.y; A[r*16+10] += s * v2.z; A[r*16+11] += s * v2.w;
                A[r*16+12] += s * v3.x; A[r*16+13] += s * v3.y; A[r*16+14] += s * v3.z; A[r*16+15] += s * v3.w;
            }
        }
        // reduce-and-distribute across lanes: after 6 folds, lane l holds total of A[l]
#define FOLD(OFF, HALF)                                                   \
        {                                                                 \
            const bool hi = (lane & OFF) != 0;                            \
            _Pragma("unroll")                                             \
            for (int i2 = 0; i2 < HALF; ++i2) {                           \
                const float a = A[i2], b = A[i2 + HALF];                  \
                float keep = hi ? b : a;                                  \
                const float send = hi ? a : b;                            \
                keep += __shfl_xor(send, OFF, 64);                        \
                A[i2] = keep;                                             \
            }                                                             \
        }
        FOLD(32, 32) FOLD(16, 16) FOLD(8, 8) FOLD(4, 4) FOLD(2, 2) FOLD(1, 1)
#undef FOLD
        red[w][lane] = A[0];
    }
    __syncthreads();
    if (t < 64) {
        const int r = t >> 4, d = t & 15;
        const float v = (red[0][t] + red[1][t] + red[2][t] + red[3][t]) * inv_s[r];
        OT[(size_t)(i0 + r) * kE + h * kD + d] = v;
    }
}

// ---------------- Kernel 3: output projection (in-place safe: row staged in LDS) ----------------
__global__ void out_proj_kernel(const float* __restrict__ OT, const float* __restrict__ Wo,
                                const float* __restrict__ bo, float* __restrict__ out) {
    const int n = blockIdx.x, f = threadIdx.x;
    __shared__ float x[kE];
    x[f] = OT[n * kE + f];
    __syncthreads();
    float a = bo[f];
#pragma unroll 8
    for (int e = 0; e < kE; ++e) a += x[e] * Wo[e * kE + f];
    out[n * kE + f] = a;
}

extern "C" void kernel_launch(void* const* d_in, const int* in_sizes, int n_in,
                              void* d_out, int out_size, void* d_ws, size_t ws_size,
                              hipStream_t stream) {
    const float* query = (const float*)d_in[0];
    const float* key_  = (const float*)d_in[1];
    const float* value = (const float*)d_in[2];
    const float* Wq    = (const float*)d_in[3];
    const float* bq    = (const float*)d_in[4];
    const float* Wk    = (const float*)d_in[5];
    const float* bk    = (const float*)d_in[6];
    const float* Wv    = (const float*)d_in[7];
    const float* bv    = (const float*)d_in[8];
    const float* ebias = (const float*)d_in[9];
    const float* Wo    = (const float*)d_in[10];
    const float* bo    = (const float*)d_in[11];
    const int* node_types = (const int*)d_in[12];
    const int* edge_index = (const int*)d_in[13];
    const int* edge_types = (const int*)d_in[14];

    float* out  = (float*)d_out;
    float* attn = (float*)d_out + (size_t)kN * kE;  // [H,N,N] output region

    float* ws = (float*)d_ws;
    float* Q = ws;                        // [N,E]
    float* K = ws + (size_t)kN * kE;      // [N,E]
    float* V = ws + 2 * (size_t)kN * kE;  // [N,E]
    int* counts = (int*)(ws + 3 * (size_t)kN * kE);      // [N]
    int* P      = counts + kN;                           // [N] starts -> ends after scatter
    unsigned short* entries = (unsigned short*)(P + kN); // [NE]
    float* OT = out;  // stage attn@V in the final-out region (out_proj is in-place safe)

    proj_kernel<<<kN, kE, 0, stream>>>(query, key_, value, Wq, bq, Wk, bk, Wv, bv,
                                       node_types, Q, K, V);
    csr_zero_kernel<<<kN / 256, 256, 0, stream>>>(counts);
    csr_count_kernel<<<kNE / 256, 256, 0, stream>>>(edge_index, counts);
    csr_scan_kernel<<<1, 1024, 0, stream>>>(counts, P);
    csr_scatter_kernel<<<kNE / 256, 256, 0, stream>>>(edge_index, edge_types, P, entries);
    attn_fused_kernel<<<dim3(kN / 4, kH), 256, 0, stream>>>(Q, K, V, P, entries, ebias,
                                                            attn, OT);
    out_proj_kernel<<<kN, kE, 0, stream>>>(OT, Wo, bo, out);
}